// Round 10
// baseline (273.609 us; speedup 1.0000x reference)
//
#include <hip/hip_runtime.h>
#include <hip/hip_bf16.h>
#include <math.h>

#define N_TOK 16384
#define DIM   256
#define HID   512
#define NEXP  16
#define NSLOT (N_TOK * 2)
#define RT    64
#define MAXT  (NSLOT / RT + NEXP)   // 528 = 8*66
#define XCDC  (MAXT / 8)            // 66

typedef __attribute__((ext_vector_type(8))) short bf16x8;
typedef __attribute__((ext_vector_type(4))) float f32x4;
#define MFMA(a, b, c) __builtin_amdgcn_mfma_f32_16x16x32_bf16(a, b, c, 0, 0, 0)

__device__ __forceinline__ unsigned short f2b(float f) {
  union { float f; unsigned int i; } c; c.f = f;
  unsigned int r = c.i + 0x7FFFu + ((c.i >> 16) & 1u);  // RNE
  return (unsigned short)(r >> 16);
}

// tanh-form GELU via hw exp2/rcp
__device__ __forceinline__ float gelu_f(float v) {
  float v2 = v * v;
  float u2 = v * fmaf(0.10294322f, v2, 2.3022082f);
  float s  = __builtin_amdgcn_exp2f(u2);
  float r  = __builtin_amdgcn_rcpf(1.0f + s);
  return fmaf(-v, r, v);
}

// ---------- merged prep (blocks 0..4095) + router (blocks 4096..8191) ----------
__global__ __launch_bounds__(256) void prep_router_kernel(
    const float* __restrict__ W1, const float* __restrict__ W2,
    const float* __restrict__ x, const float* __restrict__ Wr,
    unsigned short* __restrict__ W1f, unsigned short* __restrict__ W2f,
    float* __restrict__ probs_out, float* __restrict__ topi_out,
    float* __restrict__ topw, int* __restrict__ sel, float* __restrict__ g_partial,
    unsigned short* __restrict__ xb)
{
  if (blockIdx.x < 4096) {
    // ---- prep: W1,W2 -> bf16 fragment-major ----
    int id = blockIdx.x * 256 + threadIdx.x;
    if (id < 524288) {                       // W1f: ((e*8+kb)*512+h)*32 + (d%32)
      int i4 = id * 4;
      int inner = i4 & 31;
      int h  = (i4 >> 5) & 511;
      int kb = (i4 >> 14) & 7;
      int e  = i4 >> 17;
      const float* src = W1 + ((size_t)(e * 256 + kb * 32 + inner) * 512 + h);
      ushort4 o;
      o.x = f2b(src[0]); o.y = f2b(src[512]); o.z = f2b(src[1024]); o.w = f2b(src[1536]);
      *(ushort4*)(W1f + i4) = o;
    } else {                                 // W2f: ((e*16+kb)*256+d2)*32 + (h%32)
      int i4 = (id - 524288) * 4;
      int inner = i4 & 31;
      int d2 = (i4 >> 5) & 255;
      int kb = (i4 >> 13) & 15;
      int e  = i4 >> 17;
      const float* src = W2 + ((size_t)(e * 512 + kb * 32 + inner) * 256 + d2);
      ushort4 o;
      o.x = f2b(src[0]); o.y = f2b(src[256]); o.z = f2b(src[512]); o.w = f2b(src[768]);
      *(ushort4*)(W2f + i4) = o;
    }
    return;
  }

  // ---- router: one wave per token ----
  __shared__ float sp[16];
  int bid = blockIdx.x - 4096;
  int tid = threadIdx.x;
  int wv = tid >> 6, lane = tid & 63;
  int tok = bid * 4 + wv;
  int e = lane & 15, q = lane >> 4;
  if (tid < 16) sp[tid] = 0.f;
  __syncthreads();

  const float4* xr = (const float4*)(x + (size_t)tok * DIM + q * 64);
  const float4* wr = (const float4*)(Wr + (size_t)e * DIM + q * 64);
  float a0 = 0.f, a1 = 0.f, a2 = 0.f, a3 = 0.f;
  #pragma unroll
  for (int i = 0; i < 16; ++i) {
    float4 xa = xr[i], wa = wr[i];
    a0 += xa.x * wa.x; a1 += xa.y * wa.y; a2 += xa.z * wa.z; a3 += xa.w * wa.w;
  }
  float lg = (a0 + a1) + (a2 + a3);
  lg += __shfl_xor(lg, 16, 64);
  lg += __shfl_xor(lg, 32, 64);           // every lane: full logit for its e

  float mx = lg;
  #pragma unroll
  for (int o = 1; o < 16; o <<= 1) mx = fmaxf(mx, __shfl_xor(mx, o, 64));
  float ex = expf(lg - mx);
  float ssum = ex;
  #pragma unroll
  for (int o = 1; o < 16; o <<= 1) ssum += __shfl_xor(ssum, o, 64);
  float p = ex / ssum;

  if (lane < 16) {
    probs_out[(size_t)tok * NEXP + e] = p;
    atomicAdd(&sp[e], p);
  }

  // bf16 copy of this token's x row (coalesced)
  {
    float4 xc = *(const float4*)(x + (size_t)tok * DIM + lane * 4);
    ushort4 o;
    o.x = f2b(xc.x); o.y = f2b(xc.y); o.z = f2b(xc.z); o.w = f2b(xc.w);
    *(ushort4*)(xb + (size_t)tok * DIM + lane * 4) = o;
  }

  // top-2 argmax (strict >, low index wins)
  float p1 = p; int i1 = e;
  #pragma unroll
  for (int o = 1; o < 16; o <<= 1) {
    float po = __shfl_xor(p1, o, 64); int io = __shfl_xor(i1, o, 64);
    if (po > p1 || (po == p1 && io < i1)) { p1 = po; i1 = io; }
  }
  float pm = (e == i1) ? -1.f : p;
  float p2 = pm; int i2 = e;
  #pragma unroll
  for (int o = 1; o < 16; o <<= 1) {
    float po = __shfl_xor(p2, o, 64); int io = __shfl_xor(i2, o, 64);
    if (po > p2 || (po == p2 && io < i2)) { p2 = po; i2 = io; }
  }
  if (lane == 0) {
    float rs = 1.0f / (p1 + p2 + 1e-9f);
    int s0 = tok * 2;
    topw[s0] = p1 * rs;  topw[s0 + 1] = p2 * rs;
    sel[s0] = i1;        sel[s0 + 1] = i2;
    topi_out[s0] = (float)i1;  topi_out[s0 + 1] = (float)i2;
  }
  __syncthreads();
  if (tid < 16) g_partial[(size_t)tid * 4096 + bid] = sp[tid];
}

// ---------- scatter: bucket fill (slot ids) + last-block stats ----------
__global__ __launch_bounds__(256) void scatter_kernel(
    const int* __restrict__ sel, const float* __restrict__ topw,
    const float* __restrict__ g_partial,
    int* __restrict__ cursors, int* __restrict__ gdone,
    int* __restrict__ slotA, float* __restrict__ w_of_pos,
    int* __restrict__ perm, float* __restrict__ lb_out)
{
  __shared__ int bcnt[16];
  __shared__ int bbase[16];
  int tid = threadIdx.x;
  if (tid < 16) bcnt[tid] = 0;
  __syncthreads();
  int s = blockIdx.x * 256 + tid;      // NSLOT = 128*256 exact
  int e = sel[s];
  int my = atomicAdd(&bcnt[e], 1);
  __syncthreads();
  if (tid < 16) bbase[tid] = atomicAdd(&cursors[tid], bcnt[tid]);
  __syncthreads();
  int idx = e * NSLOT + bbase[e] + my;
  slotA[idx]    = s;
  w_of_pos[idx] = topw[s];

  // last block: stats (lb_loss + XCD-grouped tile table)
  __threadfence();
  __shared__ int lastS;
  if (tid == 0) lastS = (atomicAdd(gdone, 1) == 127) ? 1 : 0;
  __syncthreads();
  if (!lastS) return;

  __shared__ float sp[16];
  __shared__ int nt[16];
  __shared__ int P[9];
  __shared__ int ccnt[16];
  int wv = tid >> 6, lane = tid & 63;
  if (tid < 16) ccnt[tid] = atomicAdd(&cursors[tid], 0);   // coherent read
  #pragma unroll
  for (int ee = 0; ee < 4; ++ee) {
    int ex = wv * 4 + ee;
    float sacc = 0.f;
    #pragma unroll
    for (int j = 0; j < 64; ++j) sacc += g_partial[(size_t)ex * 4096 + j * 64 + lane];
    #pragma unroll
    for (int o = 32; o; o >>= 1) sacc += __shfl_xor(sacc, o, 64);
    if (lane == 0) sp[ex] = sacc;
  }
  __syncthreads();
  if (tid < 16) nt[tid] = (ccnt[tid] + RT - 1) / RT;
  __syncthreads();
  if (tid == 0) {
    float acc = 0.f;
    for (int e2 = 0; e2 < NEXP; ++e2)
      acc += ((float)ccnt[e2] / (32768.0f + 1e-9f)) * (sp[e2] * (1.0f / 16384.0f));
    lb_out[0] = 0.01f * 16.0f * acc;
    int pp = 0;
    for (int g = 0; g < 8; ++g) { P[g] = pp; pp += nt[g] + nt[g + 8]; }
    P[8] = pp;
  }
  __syncthreads();
  for (int t = tid; t < MAXT; t += 256) {
    int g = 0;
    #pragma unroll
    for (int gg = 1; gg < 8; ++gg) if (t >= P[gg]) g = gg;
    int v = -1;
    if (t < P[8]) {
      int r = t - P[g];
      int e2 = (r < nt[g]) ? g : g + 8;
      int mt = (r < nt[g]) ? r : r - nt[g];
      v = (e2 << 16) | mt;
    }
    perm[t] = v;
  }
}

// ---------- fused FFN: RT=64, 4 waves, split-Hs two-phase, bf16 ybuf stores ----------
__global__ __launch_bounds__(256, 2) void ffn_kernel(
    const unsigned short* __restrict__ xb,
    const unsigned short* __restrict__ W1f, const unsigned short* __restrict__ W2f,
    const int* __restrict__ cursors, const int* __restrict__ perm,
    const int* __restrict__ slotA, const float* __restrict__ w_of_pos,
    unsigned short* __restrict__ ybuf)
{
  __shared__ __align__(16) unsigned short As[8 * 64 * 32];    // 32 KB
  __shared__ __align__(16) unsigned short Hs[8 * 64 * 32];    // 32 KB (half of H)
  __shared__ float rwS[RT];
  __shared__ int   slotS[RT];

  int b = blockIdx.x;
  int rr = (b & 7) * XCDC + (b >> 3);       // XCD-pinned tile pick
  int pv = perm[rr];
  if (pv < 0) return;
  int e = pv >> 16, mtile = pv & 0xFFFF;
  int cnt = cursors[e];
  int base = e * NSLOT;
  int m0 = mtile * RT;

  int tid = threadIdx.x;
  if (tid < RT) {
    int rl = m0 + tid;
    slotS[tid] = (rl < cnt) ? slotA[base + rl] : -1;
    rwS[tid]   = (rl < cnt) ? w_of_pos[base + rl] : 0.f;
  }
  __syncthreads();

  // gather 64 X rows into As (swizzled fragment layout): 2048 chunks / 256 threads
  #pragma unroll
  for (int q = 0; q < 8; ++q) {
    int idx = q * 256 + tid;
    int row = idx >> 5, cb = idx & 31;
    int s = slotS[row];
    bf16x8 v = {0, 0, 0, 0, 0, 0, 0, 0};
    if (s >= 0) v = *(const bf16x8*)(xb + (size_t)(s >> 1) * DIM + cb * 8);
    int si = ((cb >> 2) * 2048 + row * 32 + (cb & 3) * 8) ^ ((row & 7) << 3);
    *(bf16x8*)&As[si] = v;
  }
  __syncthreads();

  int lane = tid & 63;
  int w = tid >> 6;              // wave 0..3
  int l15 = lane & 15, g = lane >> 4;

  // A-frags for all 4 row-blocks (128 VGPR, live through both GEMM1 phases)
  bf16x8 af[4][8];
  #pragma unroll
  for (int mf = 0; mf < 4; ++mf) {
    int row = mf * 16 + l15;
    #pragma unroll
    for (int kb = 0; kb < 8; ++kb)
      af[mf][kb] = *(const bf16x8*)&As[(kb * 2048 + row * 32 + g * 8) ^ ((row & 7) << 3)];
  }

  // persistent GEMM2 accumulators: wave owns y cols [w*64, +64) -> acY[cf][mf]
  f32x4 acY[4][4];
  #pragma unroll
  for (int cf = 0; cf < 4; ++cf)
    #pragma unroll
    for (int mf = 0; mf < 4; ++mf) acY[cf][mf] = (f32x4){0.f, 0.f, 0.f, 0.f};

  const unsigned short* W1e = W1f + (size_t)e * (8 * 512 * 32);
  const unsigned short* W2e = W2f + (size_t)e * (16 * 256 * 32);

  #pragma unroll
  for (int ph = 0; ph < 2; ++ph) {
    // ---- GEMM1 phase: H(:, ph*256 + [0,256)) -> Hs; wave w owns 64 h-cols ----
    #pragma unroll
    for (int cf = 0; cf < 4; ++cf) {
      int col = ph * 256 + w * 64 + cf * 16;     // global h col0 (+l15)
      f32x4 ac[4];
      #pragma unroll
      for (int mf = 0; mf < 4; ++mf) ac[mf] = (f32x4){0.f, 0.f, 0.f, 0.f};
      #pragma unroll
      for (int kb = 0; kb < 8; ++kb) {
        bf16x8 bfr = *(const bf16x8*)(W1e + (size_t)(kb * 512 + col + l15) * 32 + g * 8);
        #pragma unroll
        for (int mf = 0; mf < 4; ++mf) ac[mf] = MFMA(af[mf][kb], bfr, ac[mf]);
      }
      int colL = w * 64 + cf * 16 + l15;         // local col within half
      #pragma unroll
      for (int mf = 0; mf < 4; ++mf) {
        #pragma unroll
        for (int reg = 0; reg < 4; ++reg) {
          int row = mf * 16 + g * 4 + reg;
          int si = ((colL >> 5) * 2048 + row * 32 + (colL & 31)) ^ ((row & 7) << 3);
          Hs[si] = f2b(gelu_f(ac[mf][reg]));
        }
      }
    }
    __syncthreads();

    // ---- GEMM2 partial: kb = ph*8 + kbL; wave w owns y cols [w*64, +64) ----
    #pragma unroll
    for (int kbL = 0; kbL < 8; ++kbL) {
      int kb = ph * 8 + kbL;
      bf16x8 hfr[4];
      #pragma unroll
      for (int mf = 0; mf < 4; ++mf) {
        int row = mf * 16 + l15;
        hfr[mf] = *(const bf16x8*)&Hs[(kbL * 2048 + row * 32 + g * 8) ^ ((row & 7) << 3)];
      }
      #pragma unroll
      for (int cf = 0; cf < 4; ++cf) {
        bf16x8 b2 = *(const bf16x8*)(W2e + (size_t)(kb * 256 + w * 64 + cf * 16 + l15) * 32 + g * 8);
        #pragma unroll
        for (int mf = 0; mf < 4; ++mf) acY[cf][mf] = MFMA(hfr[mf], b2, acY[cf][mf]);
      }
    }
    if (ph == 0) __syncthreads();   // before GEMM1 phase B overwrites Hs
  }

  // ---- epilogue: y * w -> bf16 ybuf[slot] (plain coalesced stores) ----
  #pragma unroll
  for (int mf = 0; mf < 4; ++mf) {
    #pragma unroll
    for (int reg = 0; reg < 4; ++reg) {
      int row = mf * 16 + g * 4 + reg;
      int s = slotS[row];
      if (s >= 0) {
        float rw = rwS[row];
        unsigned short* yp = ybuf + (size_t)s * DIM + w * 64 + l15;
        #pragma unroll
        for (int cf = 0; cf < 4; ++cf)
          yp[cf * 16] = f2b(acY[cf][mf][reg] * rw);
      }
    }
  }
}

// ---------- combine + residual + LayerNorm (streaming, no gather) ----------
__global__ __launch_bounds__(256) void combine_ln_kernel(
    const float* __restrict__ x, const unsigned short* __restrict__ ybuf,
    const float* __restrict__ gamma, const float* __restrict__ beta,
    float* __restrict__ outp)
{
  int wv = threadIdx.x >> 6, lane = threadIdx.x & 63;
  int tok = blockIdx.x * 4 + wv;
  int d0 = lane << 2;
  float4 xv = *(const float4*)(x + (size_t)tok * DIM + d0);
  ushort4 u0 = *(const ushort4*)(ybuf + (size_t)(tok * 2) * DIM + d0);
  ushort4 u1 = *(const ushort4*)(ybuf + (size_t)(tok * 2 + 1) * DIM + d0);
  union { unsigned int i; float f; } c0, c1, c2, c3, d1, d2_, d3, d4;
  c0.i = (unsigned int)u0.x << 16; c1.i = (unsigned int)u0.y << 16;
  c2.i = (unsigned int)u0.z << 16; c3.i = (unsigned int)u0.w << 16;
  d1.i = (unsigned int)u1.x << 16; d2_.i = (unsigned int)u1.y << 16;
  d3.i = (unsigned int)u1.z << 16; d4.i = (unsigned int)u1.w << 16;
  float z0 = xv.x + c0.f + d1.f;
  float z1 = xv.y + c1.f + d2_.f;
  float z2 = xv.z + c2.f + d3.f;
  float z3 = xv.w + c3.f + d4.f;
  float s = z0 + z1 + z2 + z3;
  float q = z0 * z0 + z1 * z1 + z2 * z2 + z3 * z3;
  #pragma unroll
  for (int off = 32; off > 0; off >>= 1) {
    s += __shfl_xor(s, off, 64);
    q += __shfl_xor(q, off, 64);
  }
  float mu  = s * (1.0f / 256.0f);
  float var = q * (1.0f / 256.0f) - mu * mu;
  float inv = rsqrtf(var + 1e-5f);
  float4 gv = *(const float4*)(gamma + d0);
  float4 bv = *(const float4*)(beta + d0);
  float4 ov;
  ov.x = (z0 - mu) * inv * gv.x + bv.x;
  ov.y = (z1 - mu) * inv * gv.y + bv.y;
  ov.z = (z2 - mu) * inv * gv.z + bv.z;
  ov.w = (z3 - mu) * inv * gv.w + bv.w;
  *(float4*)(outp + (size_t)tok * DIM + d0) = ov;
}

extern "C" void kernel_launch(void* const* d_in, const int* in_sizes, int n_in,
                              void* d_out, int out_size, void* d_ws, size_t ws_size,
                              hipStream_t stream)
{
  const float* x     = (const float*)d_in[0];
  const float* Wr    = (const float*)d_in[1];
  const float* W1    = (const float*)d_in[2];
  const float* W2    = (const float*)d_in[3];
  const float* gamma = (const float*)d_in[4];
  const float* beta  = (const float*)d_in[5];

  float* ob = (float*)d_out;
  float* out_main  = ob;
  float* lb_out    = ob + (size_t)N_TOK * DIM;
  float* probs_out = ob + (size_t)N_TOK * DIM + 1;
  float* topi_out  = ob + (size_t)N_TOK * DIM + 1 + (size_t)N_TOK * NEXP;

  char* ws = (char*)d_ws;
  int*   cursors    = (int*)(ws + 0);                    // 64 B [zeroed]
  int*   gdone      = (int*)(ws + 64);                   // 4 B  [zeroed]
  int*   perm       = (int*)(ws + 1024);                 // 528 ints
  float* g_partial  = (float*)(ws + 65536);              // 256 KB
  float* topw       = (float*)(ws + 327680);             // 128 KB
  int*   sel        = (int*)(ws + 458752);               // 128 KB
  int*   slotA      = (int*)(ws + 589824);               // 2 MB (16 arenas x 32768)
  float* w_of_pos   = (float*)(ws + 2686976);            // 2 MB
  unsigned short* xb  = (unsigned short*)(ws + 4980736);    // 8 MB
  unsigned short* W1f = (unsigned short*)(ws + 13369344);   // 4 MB
  unsigned short* W2f = (unsigned short*)(ws + 17563648);   // 4 MB
  unsigned short* ybuf = (unsigned short*)(ws + 21757952);  // 16 MB; total ~37 MB

  hipMemsetAsync(cursors, 0, 128, stream);
  prep_router_kernel<<<8192, 256, 0, stream>>>(W1, W2, x, Wr, W1f, W2f,
                                               probs_out, topi_out, topw, sel, g_partial, xb);
  scatter_kernel<<<NSLOT / 256, 256, 0, stream>>>(sel, topw, g_partial, cursors, gdone,
                                                  slotA, w_of_pos, perm, lb_out);
  ffn_kernel<<<MAXT, 256, 0, stream>>>(xb, W1f, W2f, cursors, perm, slotA, w_of_pos, ybuf);
  combine_ln_kernel<<<N_TOK / 4, 256, 0, stream>>>(x, ybuf, gamma, beta, out_main);
}

// Round 11
// 199.264 us; speedup vs baseline: 1.3731x; 1.3731x over previous
//
#include <hip/hip_runtime.h>
#include <hip/hip_bf16.h>
#include <math.h>

#define N_TOK 16384
#define DIM   256
#define HID   512
#define NEXP  16
#define NSLOT (N_TOK * 2)
#define RT    64
#define MAXT  (NSLOT / RT + NEXP)   // 528 = 8*66
#define XCDC  (MAXT / 8)            // 66

typedef __attribute__((ext_vector_type(8))) short bf16x8;
typedef __attribute__((ext_vector_type(4))) float f32x4;
#define MFMA(a, b, c) __builtin_amdgcn_mfma_f32_16x16x32_bf16(a, b, c, 0, 0, 0)

__device__ __forceinline__ unsigned short f2b(float f) {
  union { float f; unsigned int i; } c; c.f = f;
  unsigned int r = c.i + 0x7FFFu + ((c.i >> 16) & 1u);  // RNE
  return (unsigned short)(r >> 16);
}

// tanh-form GELU via hw exp2/rcp
__device__ __forceinline__ float gelu_f(float v) {
  float v2 = v * v;
  float u2 = v * fmaf(0.10294322f, v2, 2.3022082f);
  float s  = __builtin_amdgcn_exp2f(u2);
  float r  = __builtin_amdgcn_rcpf(1.0f + s);
  return fmaf(-v, r, v);
}

// ---------- merged: W1 transpose [0,512) | W2 transpose [512,1024) | router [1024,5120) ----------
__global__ __launch_bounds__(256) void prep_router_kernel(
    const float* __restrict__ W1, const float* __restrict__ W2,
    const float* __restrict__ x, const float* __restrict__ Wr,
    unsigned short* __restrict__ W1f, unsigned short* __restrict__ W2f,
    float* __restrict__ probs_out, float* __restrict__ topi_out,
    float* __restrict__ topw, int* __restrict__ sel, float* __restrict__ g_partial,
    unsigned short* __restrict__ xb, int* __restrict__ wszero)
{
  int tid = threadIdx.x;
  if (blockIdx.x < 1024) {
    __shared__ float tile[128][33];
    if (blockIdx.x == 0 && tid < 32) wszero[tid] = 0;   // cursors+gdone (stream-ordered before scatter)
    int inner = tid >> 3;           // 0..31 (load phase row)
    int hq    = tid & 7;
    int inner4 = (tid & 7) * 4;     // write phase
    int hh     = tid >> 3;          // 0..31
    if (blockIdx.x < 512) {
      // ---- W1: src [e][kb*32+inner][512 h] -> dst ((e*8+kb)*512+h)*32+inner ----
      int b = blockIdx.x;
      int e = b >> 5, kb = (b >> 2) & 7, h0 = (b & 3) * 128;
      const float* src = W1 + ((size_t)(e * 256 + kb * 32 + inner) * 512 + h0);
      #pragma unroll
      for (int p = 0; p < 4; ++p) {
        int h = hq * 4 + p * 32;
        float4 v = *(const float4*)(src + h);
        tile[h][inner] = v.x; tile[h + 1][inner] = v.y;
        tile[h + 2][inner] = v.z; tile[h + 3][inner] = v.w;
      }
      __syncthreads();
      unsigned short* dst = W1f + ((size_t)(e * 8 + kb) * 512 + h0) * 32;
      #pragma unroll
      for (int p = 0; p < 4; ++p) {
        int h = hh + p * 32;
        ushort4 o;
        o.x = f2b(tile[h][inner4]);     o.y = f2b(tile[h][inner4 + 1]);
        o.z = f2b(tile[h][inner4 + 2]); o.w = f2b(tile[h][inner4 + 3]);
        *(ushort4*)(dst + (size_t)h * 32 + inner4) = o;
      }
    } else {
      // ---- W2: src [e][kb*32+inner][256 d] -> dst ((e*16+kb)*256+d)*32+inner ----
      int b = blockIdx.x - 512;
      int e = b >> 5, kb = (b >> 1) & 15, d0 = (b & 1) * 128;
      const float* src = W2 + ((size_t)(e * 512 + kb * 32 + inner) * 256 + d0);
      #pragma unroll
      for (int p = 0; p < 4; ++p) {
        int d = hq * 4 + p * 32;
        float4 v = *(const float4*)(src + d);
        tile[d][inner] = v.x; tile[d + 1][inner] = v.y;
        tile[d + 2][inner] = v.z; tile[d + 3][inner] = v.w;
      }
      __syncthreads();
      unsigned short* dst = W2f + ((size_t)(e * 16 + kb) * 256 + d0) * 32;
      #pragma unroll
      for (int p = 0; p < 4; ++p) {
        int d = hh + p * 32;
        ushort4 o;
        o.x = f2b(tile[d][inner4]);     o.y = f2b(tile[d][inner4 + 1]);
        o.z = f2b(tile[d][inner4 + 2]); o.w = f2b(tile[d][inner4 + 3]);
        *(ushort4*)(dst + (size_t)d * 32 + inner4) = o;
      }
    }
    return;
  }

  // ---- router: one wave per token ----
  __shared__ float sp[16];
  int bid = blockIdx.x - 1024;
  int wv = tid >> 6, lane = tid & 63;
  int tok = bid * 4 + wv;
  int e = lane & 15, q = lane >> 4;
  if (tid < 16) sp[tid] = 0.f;
  __syncthreads();

  const float4* xr = (const float4*)(x + (size_t)tok * DIM + q * 64);
  const float4* wr = (const float4*)(Wr + (size_t)e * DIM + q * 64);
  float a0 = 0.f, a1 = 0.f, a2 = 0.f, a3 = 0.f;
  #pragma unroll
  for (int i = 0; i < 16; ++i) {
    float4 xa = xr[i], wa = wr[i];
    a0 += xa.x * wa.x; a1 += xa.y * wa.y; a2 += xa.z * wa.z; a3 += xa.w * wa.w;
  }
  float lg = (a0 + a1) + (a2 + a3);
  lg += __shfl_xor(lg, 16, 64);
  lg += __shfl_xor(lg, 32, 64);           // every lane: full logit for its e

  float mx = lg;
  #pragma unroll
  for (int o = 1; o < 16; o <<= 1) mx = fmaxf(mx, __shfl_xor(mx, o, 64));
  float ex = expf(lg - mx);
  float ssum = ex;
  #pragma unroll
  for (int o = 1; o < 16; o <<= 1) ssum += __shfl_xor(ssum, o, 64);
  float p = ex / ssum;

  if (lane < 16) {
    probs_out[(size_t)tok * NEXP + e] = p;
    atomicAdd(&sp[e], p);
  }

  // bf16 copy of this token's x row (coalesced)
  {
    float4 xc = *(const float4*)(x + (size_t)tok * DIM + lane * 4);
    ushort4 o;
    o.x = f2b(xc.x); o.y = f2b(xc.y); o.z = f2b(xc.z); o.w = f2b(xc.w);
    *(ushort4*)(xb + (size_t)tok * DIM + lane * 4) = o;
  }

  // top-2 argmax (strict >, low index wins)
  float p1 = p; int i1 = e;
  #pragma unroll
  for (int o = 1; o < 16; o <<= 1) {
    float po = __shfl_xor(p1, o, 64); int io = __shfl_xor(i1, o, 64);
    if (po > p1 || (po == p1 && io < i1)) { p1 = po; i1 = io; }
  }
  float pm = (e == i1) ? -1.f : p;
  float p2 = pm; int i2 = e;
  #pragma unroll
  for (int o = 1; o < 16; o <<= 1) {
    float po = __shfl_xor(p2, o, 64); int io = __shfl_xor(i2, o, 64);
    if (po > p2 || (po == p2 && io < i2)) { p2 = po; i2 = io; }
  }
  if (lane == 0) {
    float rs = 1.0f / (p1 + p2 + 1e-9f);
    int s0 = tok * 2;
    topw[s0] = p1 * rs;  topw[s0 + 1] = p2 * rs;
    sel[s0] = i1;        sel[s0 + 1] = i2;
    topi_out[s0] = (float)i1;  topi_out[s0 + 1] = (float)i2;
  }
  __syncthreads();
  if (tid < 16) g_partial[(size_t)tid * 4096 + bid] = sp[tid];
}

// ---------- scatter: bucket fill (slot ids) + last-block stats ----------
__global__ __launch_bounds__(256) void scatter_kernel(
    const int* __restrict__ sel, const float* __restrict__ topw,
    const float* __restrict__ g_partial,
    int* __restrict__ cursors, int* __restrict__ gdone,
    int* __restrict__ slotA, float* __restrict__ w_of_pos,
    int* __restrict__ perm, float* __restrict__ lb_out)
{
  __shared__ int bcnt[16];
  __shared__ int bbase[16];
  int tid = threadIdx.x;
  if (tid < 16) bcnt[tid] = 0;
  __syncthreads();
  int s = blockIdx.x * 256 + tid;      // NSLOT = 128*256 exact
  int e = sel[s];
  int my = atomicAdd(&bcnt[e], 1);
  __syncthreads();
  if (tid < 16) bbase[tid] = atomicAdd(&cursors[tid], bcnt[tid]);
  __syncthreads();
  int idx = e * NSLOT + bbase[e] + my;
  slotA[idx]    = s;
  w_of_pos[idx] = topw[s];

  // last block: stats (lb_loss + XCD-grouped tile table)
  __threadfence();
  __shared__ int lastS;
  if (tid == 0) lastS = (atomicAdd(gdone, 1) == 127) ? 1 : 0;
  __syncthreads();
  if (!lastS) return;

  __shared__ float sp[16];
  __shared__ int nt[16];
  __shared__ int P[9];
  __shared__ int ccnt[16];
  int wv = tid >> 6, lane = tid & 63;
  if (tid < 16) ccnt[tid] = atomicAdd(&cursors[tid], 0);   // coherent read
  #pragma unroll
  for (int ee = 0; ee < 4; ++ee) {
    int ex = wv * 4 + ee;
    float sacc = 0.f;
    #pragma unroll
    for (int j = 0; j < 64; ++j) sacc += g_partial[(size_t)ex * 4096 + j * 64 + lane];
    #pragma unroll
    for (int o = 32; o; o >>= 1) sacc += __shfl_xor(sacc, o, 64);
    if (lane == 0) sp[ex] = sacc;
  }
  __syncthreads();
  if (tid < 16) nt[tid] = (ccnt[tid] + RT - 1) / RT;
  __syncthreads();
  if (tid == 0) {
    float acc = 0.f;
    for (int e2 = 0; e2 < NEXP; ++e2)
      acc += ((float)ccnt[e2] / (32768.0f + 1e-9f)) * (sp[e2] * (1.0f / 16384.0f));
    lb_out[0] = 0.01f * 16.0f * acc;
    int pp = 0;
    for (int g = 0; g < 8; ++g) { P[g] = pp; pp += nt[g] + nt[g + 8]; }
    P[8] = pp;
  }
  __syncthreads();
  for (int t = tid; t < MAXT; t += 256) {
    int g = 0;
    #pragma unroll
    for (int gg = 1; gg < 8; ++gg) if (t >= P[gg]) g = gg;
    int v = -1;
    if (t < P[8]) {
      int r = t - P[g];
      int e2 = (r < nt[g]) ? g : g + 8;
      int mt = (r < nt[g]) ? r : r - nt[g];
      v = (e2 << 16) | mt;
    }
    perm[t] = v;
  }
}

// ---------- fused FFN (r9 body): RT=64, 8 waves, full Hs, swizzled LDS; bf16 ybuf stores ----------
__global__ __launch_bounds__(512, 1) void ffn_kernel(
    const unsigned short* __restrict__ xb,
    const unsigned short* __restrict__ W1f, const unsigned short* __restrict__ W2f,
    const int* __restrict__ cursors, const int* __restrict__ perm,
    const int* __restrict__ slotA, const float* __restrict__ w_of_pos,
    unsigned short* __restrict__ ybuf)
{
  __shared__ __align__(16) unsigned short As[8 * 64 * 32];    // 32 KB
  __shared__ __align__(16) unsigned short Hs[16 * 64 * 32];   // 64 KB
  __shared__ float rwS[RT];
  __shared__ int   slotS[RT];

  int b = blockIdx.x;
  int rr = (b & 7) * XCDC + (b >> 3);       // XCD-pinned tile pick
  int pv = perm[rr];
  if (pv < 0) return;
  int e = pv >> 16, mtile = pv & 0xFFFF;
  int cnt = cursors[e];
  int base = e * NSLOT;
  int m0 = mtile * RT;

  int tid = threadIdx.x;
  if (tid < RT) {
    int rl = m0 + tid;
    slotS[tid] = (rl < cnt) ? slotA[base + rl] : -1;
    rwS[tid]   = (rl < cnt) ? w_of_pos[base + rl] : 0.f;
  }
  __syncthreads();

  // gather 64 X rows into As (swizzled fragment layout)
  #pragma unroll
  for (int q = 0; q < 4; ++q) {
    int idx = q * 512 + tid;
    int row = idx >> 5, cb = idx & 31;
    int s = slotS[row];
    bf16x8 v = {0, 0, 0, 0, 0, 0, 0, 0};
    if (s >= 0) v = *(const bf16x8*)(xb + (size_t)(s >> 1) * DIM + cb * 8);
    int si = ((cb >> 2) * 2048 + row * 32 + (cb & 3) * 8) ^ ((row & 7) << 3);
    *(bf16x8*)&As[si] = v;
  }
  __syncthreads();

  int lane = tid & 63;
  int w = tid >> 6;              // wave 0..7
  int l15 = lane & 15, g = lane >> 4;

  // A-frags for all 4 row-blocks (dead after GEMM1)
  bf16x8 af[4][8];
  #pragma unroll
  for (int mf = 0; mf < 4; ++mf) {
    int row = mf * 16 + l15;
    #pragma unroll
    for (int kb = 0; kb < 8; ++kb)
      af[mf][kb] = *(const bf16x8*)&As[(kb * 2048 + row * 32 + g * 8) ^ ((row & 7) << 3)];
  }

  // ---- GEMM1: H = gelu(A @ W1e); wave w owns h cols [w*64, +64) ----
  const unsigned short* W1e = W1f + (size_t)e * (8 * 512 * 32);
  #pragma unroll
  for (int cf = 0; cf < 4; ++cf) {
    int col0 = w * 64 + cf * 16;
    f32x4 ac[4];
    #pragma unroll
    for (int mf = 0; mf < 4; ++mf) ac[mf] = (f32x4){0.f, 0.f, 0.f, 0.f};
    #pragma unroll
    for (int kb = 0; kb < 8; ++kb) {
      bf16x8 bfr = *(const bf16x8*)(W1e + (size_t)(kb * 512 + col0 + l15) * 32 + g * 8);
      #pragma unroll
      for (int mf = 0; mf < 4; ++mf) ac[mf] = MFMA(af[mf][kb], bfr, ac[mf]);
    }
    int col = col0 + l15;
    #pragma unroll
    for (int mf = 0; mf < 4; ++mf) {
      #pragma unroll
      for (int reg = 0; reg < 4; ++reg) {
        int row = mf * 16 + g * 4 + reg;
        int si = ((col >> 5) * 2048 + row * 32 + (col & 31)) ^ ((row & 7) << 3);
        Hs[si] = f2b(gelu_f(ac[mf][reg]));
      }
    }
  }
  __syncthreads();

  // ---- GEMM2: y = (H @ W2e) * w; wave w owns y cols [w*32, +32) ----
  const unsigned short* W2e = W2f + (size_t)e * (16 * 256 * 32);
  bf16x8 b2[2][16];
  #pragma unroll
  for (int cf = 0; cf < 2; ++cf)
    #pragma unroll
    for (int kb = 0; kb < 16; ++kb)
      b2[cf][kb] = *(const bf16x8*)(W2e + (size_t)(kb * 256 + w * 32 + cf * 16 + l15) * 32 + g * 8);

  #pragma unroll
  for (int mf = 0; mf < 4; ++mf) {
    f32x4 ac0 = {0.f, 0.f, 0.f, 0.f}, ac1 = {0.f, 0.f, 0.f, 0.f};
    int rowa = mf * 16 + l15;
    #pragma unroll
    for (int kb = 0; kb < 16; ++kb) {
      bf16x8 hfr = *(const bf16x8*)&Hs[(kb * 2048 + rowa * 32 + g * 8) ^ ((rowa & 7) << 3)];
      ac0 = MFMA(hfr, b2[0][kb], ac0);
      ac1 = MFMA(hfr, b2[1][kb], ac1);
    }
    #pragma unroll
    for (int reg = 0; reg < 4; ++reg) {
      int row = mf * 16 + g * 4 + reg;
      int s = slotS[row];
      if (s >= 0) {
        float rw = rwS[row];
        unsigned short* yp = ybuf + (size_t)s * DIM + w * 32 + l15;
        yp[0]  = f2b(ac0[reg] * rw);
        yp[16] = f2b(ac1[reg] * rw);
      }
    }
  }
}

// ---------- combine + residual + LayerNorm (streaming, no gather) ----------
__global__ __launch_bounds__(256) void combine_ln_kernel(
    const float* __restrict__ x, const unsigned short* __restrict__ ybuf,
    const float* __restrict__ gamma, const float* __restrict__ beta,
    float* __restrict__ outp)
{
  int wv = threadIdx.x >> 6, lane = threadIdx.x & 63;
  int tok = blockIdx.x * 4 + wv;
  int d0 = lane << 2;
  float4 xv = *(const float4*)(x + (size_t)tok * DIM + d0);
  ushort4 u0 = *(const ushort4*)(ybuf + (size_t)(tok * 2) * DIM + d0);
  ushort4 u1 = *(const ushort4*)(ybuf + (size_t)(tok * 2 + 1) * DIM + d0);
  union { unsigned int i; float f; } c0, c1, c2, c3, d1, d2_, d3, d4;
  c0.i = (unsigned int)u0.x << 16; c1.i = (unsigned int)u0.y << 16;
  c2.i = (unsigned int)u0.z << 16; c3.i = (unsigned int)u0.w << 16;
  d1.i = (unsigned int)u1.x << 16; d2_.i = (unsigned int)u1.y << 16;
  d3.i = (unsigned int)u1.z << 16; d4.i = (unsigned int)u1.w << 16;
  float z0 = xv.x + c0.f + d1.f;
  float z1 = xv.y + c1.f + d2_.f;
  float z2 = xv.z + c2.f + d3.f;
  float z3 = xv.w + c3.f + d4.f;
  float s = z0 + z1 + z2 + z3;
  float q = z0 * z0 + z1 * z1 + z2 * z2 + z3 * z3;
  #pragma unroll
  for (int off = 32; off > 0; off >>= 1) {
    s += __shfl_xor(s, off, 64);
    q += __shfl_xor(q, off, 64);
  }
  float mu  = s * (1.0f / 256.0f);
  float var = q * (1.0f / 256.0f) - mu * mu;
  float inv = rsqrtf(var + 1e-5f);
  float4 gv = *(const float4*)(gamma + d0);
  float4 bv = *(const float4*)(beta + d0);
  float4 ov;
  ov.x = (z0 - mu) * inv * gv.x + bv.x;
  ov.y = (z1 - mu) * inv * gv.y + bv.y;
  ov.z = (z2 - mu) * inv * gv.z + bv.z;
  ov.w = (z3 - mu) * inv * gv.w + bv.w;
  *(float4*)(outp + (size_t)tok * DIM + d0) = ov;
}

extern "C" void kernel_launch(void* const* d_in, const int* in_sizes, int n_in,
                              void* d_out, int out_size, void* d_ws, size_t ws_size,
                              hipStream_t stream)
{
  const float* x     = (const float*)d_in[0];
  const float* Wr    = (const float*)d_in[1];
  const float* W1    = (const float*)d_in[2];
  const float* W2    = (const float*)d_in[3];
  const float* gamma = (const float*)d_in[4];
  const float* beta  = (const float*)d_in[5];

  float* ob = (float*)d_out;
  float* out_main  = ob;
  float* lb_out    = ob + (size_t)N_TOK * DIM;
  float* probs_out = ob + (size_t)N_TOK * DIM + 1;
  float* topi_out  = ob + (size_t)N_TOK * DIM + 1 + (size_t)N_TOK * NEXP;

  char* ws = (char*)d_ws;
  int*   cursors    = (int*)(ws + 0);                    // 16 ints [zeroed by prep block 0]
  int*   gdone      = (int*)(ws + 64);                   // 1 int   [zeroed by prep block 0]
  int*   perm       = (int*)(ws + 1024);                 // 528 ints
  float* g_partial  = (float*)(ws + 65536);              // 256 KB
  float* topw       = (float*)(ws + 327680);             // 128 KB
  int*   sel        = (int*)(ws + 458752);               // 128 KB
  int*   slotA      = (int*)(ws + 589824);               // 2 MB (16 arenas x 32768)
  float* w_of_pos   = (float*)(ws + 2686976);            // 2 MB
  unsigned short* xb  = (unsigned short*)(ws + 4980736);    // 8 MB
  unsigned short* W1f = (unsigned short*)(ws + 13369344);   // 4 MB
  unsigned short* W2f = (unsigned short*)(ws + 17563648);   // 4 MB
  unsigned short* ybuf = (unsigned short*)(ws + 21757952);  // 16 MB; total ~37 MB

  prep_router_kernel<<<5120, 256, 0, stream>>>(W1, W2, x, Wr, W1f, W2f,
                                               probs_out, topi_out, topw, sel, g_partial,
                                               xb, (int*)ws);
  scatter_kernel<<<NSLOT / 256, 256, 0, stream>>>(sel, topw, g_partial, cursors, gdone,
                                                  slotA, w_of_pos, perm, lb_out);
  ffn_kernel<<<MAXT, 512, 0, stream>>>(xb, W1f, W2f, cursors, perm, slotA, w_of_pos, ybuf);
  combine_ln_kernel<<<N_TOK / 4, 256, 0, stream>>>(x, ybuf, gamma, beta, out_main);
}